// Round 4
// baseline (397.129 us; speedup 1.0000x reference)
//
#include <hip/hip_runtime.h>
#include <stdint.h>

#define TT 2048
#define DD 256
#define KK 1024
#define BB 16
#define NQ (BB*TT)   // 32768 queries per tensor

typedef __attribute__((ext_vector_type(8))) short short8;
typedef __attribute__((ext_vector_type(4))) short s16x4;
typedef __attribute__((ext_vector_type(4))) float f32x4;

#define AS1 __attribute__((address_space(1)))
#define AS3 __attribute__((address_space(3)))

__device__ __forceinline__ short bf16_rn(float x){
  unsigned u = __builtin_bit_cast(unsigned, x);
  unsigned r = u + 0x7fffu + ((u >> 16) & 1u);   // round-to-nearest-even
  return (short)(r >> 16);
}
__device__ __forceinline__ float bf16_to_f(short h){
  unsigned u = ((unsigned)(unsigned short)h) << 16;
  return __builtin_bit_cast(float, u);
}
// monotone float<->uint maps for atomicMin argmin keys
__device__ __forceinline__ unsigned f2o(float x){
  unsigned u = __builtin_bit_cast(unsigned, x);
  return u ^ (0x80000000u | (unsigned)((int)u >> 31));
}
__device__ __forceinline__ float o2f(unsigned m){
  unsigned u = m ^ ((m >> 31) ? 0x80000000u : 0xFFFFFFFFu);
  return __builtin_bit_cast(float, u);
}

// ---------------------------------------------------------------------------
// Fused prep: one wave per (tensor, code): swizzled bf16 hi/lo codebook,
// 0.5*|e|^2, zero counts/loss, init argmin keys to +inf.
// Swizzle: code k=(ct*16+c), dim d=(s*32+q*8+j) ->
//   pos = ((ct*8+s)*64 + (q*16+c))*8 + j   (1 KiB per (ct,s) block)
// ---------------------------------------------------------------------------
__global__ void vq_prep(const float* __restrict__ cb_top,
                        const float* __restrict__ cb_bot,
                        short* __restrict__ ws_cb,
                        float* __restrict__ e2h_all,
                        int* __restrict__ counts,
                        float* __restrict__ loss_acc,
                        unsigned long long* __restrict__ keys){
  int gid = blockIdx.x*256 + threadIdx.x;          // 512 blocks -> 131072 thr
  if (gid < 2*NQ) keys[gid] = ~0ULL;               // init argmin keys
  int wv = gid >> 6, lane = gid & 63;
  int t = wv >> 10, k = wv & 1023;
  const float* row = (t ? cb_bot : cb_top) + (size_t)k*DD;
  f32x4 v = *(const f32x4*)(row + lane*4);
  float s2 = v[0]*v[0] + v[1]*v[1] + v[2]*v[2] + v[3]*v[3];
  s16x4 hi4, lo4;
  #pragma unroll
  for (int i = 0; i < 4; ++i){
    short hi = bf16_rn(v[i]);
    hi4[i] = hi;
    lo4[i] = bf16_rn(v[i] - bf16_to_f(hi));
  }
  const int d0 = lane*4;
  const int ct = k >> 4, c = k & 15;
  const int s = d0 >> 5, q = (d0 & 31) >> 3, j = d0 & 7;
  size_t pos = ((size_t)(ct*8 + s)*64 + (q*16 + c))*8 + j;   // j in {0,4}
  short* hib = ws_cb + (size_t)t * (2*KK*DD);
  *(s16x4*)(hib + pos) = hi4;
  *(s16x4*)(hib + (size_t)KK*DD + pos) = lo4;
  #pragma unroll
  for (int off = 1; off < 64; off <<= 1) s2 += __shfl_xor(s2, off, 64);
  if (lane == 0) e2h_all[t*KK + k] = 0.5f * s2;
  if (lane == 1) counts[t*KK + k] = 0;
  if (gid == 2) { loss_acc[0] = 0.f; loss_acc[1] = 0.f; }
}

// ---------------------------------------------------------------------------
// Stage one 16-code tile (hi+lo, 16 KiB) into LDS: 16 x 1 KiB blocks,
// 4 waves x 4 width-16 global_load_lds.
// ---------------------------------------------------------------------------
__device__ __forceinline__ void prefetch_chunk(const short* cbhi, const short* cblo,
                                               short* smem, int ct, int w, int lane){
  #pragma unroll
  for (int k2 = 0; k2 < 4; ++k2){
    int bi = w*4 + k2;                              // 0..15
    int s = bi >> 1, hl = bi & 1;
    const short* src = (hl ? cblo : cbhi) + (size_t)(ct*8 + s)*512 + lane*8;
    short* dst = smem + bi*512 + lane*8;
    __builtin_amdgcn_global_load_lds((AS1 void*)src, (AS3 void*)dst, 16, 0, 0);
  }
}

// ---------------------------------------------------------------------------
// Main: G=2 (32 q/wave), codebook SPLIT in halves across blocks (ch bit) to
// double resident waves. Result merged via packed (score,idx) atomicMin.
// grid (512, 2): blockIdx.x = qt*2 + ch; 256 thr.
// ---------------------------------------------------------------------------
__global__ __launch_bounds__(256, 3) void vq_main(
    const float* __restrict__ h_top, const float* __restrict__ h_bot,
    const short* __restrict__ ws_cb, const float* __restrict__ e2h_all,
    unsigned long long* __restrict__ keys, float* __restrict__ x2g)
{
  const int tz = blockIdx.y;
  const float* __restrict__ h = tz ? h_bot : h_top;
  const short* cbhi = ws_cb + (size_t)tz * (2*KK*DD);
  const short* cblo = cbhi + KK*DD;
  const float* e2h = e2h_all + tz*KK;

  const int tid = threadIdx.x;
  const int w = tid >> 6, lane = tid & 63;
  const int c = lane & 15, q = lane >> 4;
  const int qt = blockIdx.x >> 1, ch = blockIdx.x & 1;
  const int n0 = qt*128 + w*32;                     // first query of this wave
  const int ctbase = ch*32;                         // 16-code tiles [ctbase, +32)

  __shared__ short smem[2][8192];                   // 2 x 16 KiB double buffer

  prefetch_chunk(cbhi, cblo, smem[0], ctbase, w, lane);

  // ---- prologue: 32 queries x 256 dims -> bf16 hi/lo B-fragments + |x|^2 ----
  short8 bhi[2][8], blo[2][8];
  float x2[2];
  #pragma unroll
  for (int g = 0; g < 2; ++g){
    const int n = n0 + g*16 + c;
    const float* bp = h + (size_t)(n >> 11)*((size_t)DD*TT) + (n & (TT-1))
                        + (size_t)q*8*TT;
    float xs = 0.f;
    #pragma unroll
    for (int s = 0; s < 8; ++s){
      #pragma unroll
      for (int j = 0; j < 8; ++j){
        float v = bp[(size_t)(s*32 + j)*TT];        // d = s*32 + q*8 + j
        xs += v*v;
        short hi = bf16_rn(v);
        bhi[g][s][j] = hi;
        blo[g][s][j] = bf16_rn(v - bf16_to_f(hi));
      }
    }
    x2[g] = xs;
  }

  float bestv[2] = {3.4e38f, 3.4e38f};
  int   besti[2] = {0, 0};

  __syncthreads();                                  // tile 0 resident

  for (int chunk = 0; chunk < 32; ++chunk){
    const int buf = chunk & 1;
    if (chunk + 1 < 32)
      prefetch_chunk(cbhi, cblo, smem[buf^1], ctbase + chunk + 1, w, lane);
    const short* sb = smem[buf];
    f32x4 a0 = {0,0,0,0}, a1 = {0,0,0,0};
    #pragma unroll
    for (int s = 0; s < 8; ++s){
      short8 ahi = *(const short8*)(sb + (s*2 + 0)*512 + lane*8);
      short8 alo = *(const short8*)(sb + (s*2 + 1)*512 + lane*8);
      a0 = __builtin_amdgcn_mfma_f32_16x16x32_bf16(ahi, bhi[0][s], a0, 0,0,0);
      a1 = __builtin_amdgcn_mfma_f32_16x16x32_bf16(ahi, bhi[1][s], a1, 0,0,0);
      a0 = __builtin_amdgcn_mfma_f32_16x16x32_bf16(ahi, blo[0][s], a0, 0,0,0);
      a1 = __builtin_amdgcn_mfma_f32_16x16x32_bf16(ahi, blo[1][s], a1, 0,0,0);
      a0 = __builtin_amdgcn_mfma_f32_16x16x32_bf16(alo, bhi[0][s], a0, 0,0,0);
      a1 = __builtin_amdgcn_mfma_f32_16x16x32_bf16(alo, bhi[1][s], a1, 0,0,0);
    }
    const int code0 = (ctbase + chunk)*16 + q*4;    // C: row=code, col=query
    const f32x4 e2v = *(const f32x4*)(e2h + code0);
    #pragma unroll
    for (int r = 0; r < 4; ++r){
      float s0 = e2v[r] - a0[r];                    // = (dist - |x|^2)/2
      if (s0 < bestv[0]){ bestv[0] = s0; besti[0] = code0 + r; }
      float s1 = e2v[r] - a1[r];
      if (s1 < bestv[1]){ bestv[1] = s1; besti[1] = code0 + r; }
    }
    __syncthreads();                                // drains prefetch + reuse guard
  }

  // ---- reduce across the 4 quads (codes are quad-partitioned) ----
  #pragma unroll
  for (int off = 16; off <= 32; off <<= 1){
    #pragma unroll
    for (int g = 0; g < 2; ++g){
      float ov = __shfl_xor(bestv[g], off, 64);
      int   oi = __shfl_xor(besti[g], off, 64);
      if (ov < bestv[g] || (ov == bestv[g] && oi < besti[g])){ bestv[g] = ov; besti[g] = oi; }
      x2[g] += __shfl_xor(x2[g], off, 64);
    }
  }

  // lane L < 32 owns query n0 + L  (g = L>>4, c = L&15)
  if (lane < 32){
    const int g = lane >> 4;
    const int n = n0 + lane;
    float bv = g ? bestv[1] : bestv[0];
    int   bi = g ? besti[1] : besti[0];
    unsigned long long key = ((unsigned long long)f2o(bv) << 10) | (unsigned)bi;
    atomicMin(&keys[(size_t)tz*NQ + n], key);
    if (ch == 0) x2g[(size_t)tz*NQ + n] = g ? x2[1] : x2[0];
  }
}

// ---------------------------------------------------------------------------
// Gather: resolve keys -> idx/score; z = codebook[idx] ([B,D,T] layout),
// counts, loss. grid (256, 2), 256 thr; wave = 32 queries, full 64 lanes
// used for the z write (d split by lane>>5).
// ---------------------------------------------------------------------------
__global__ void vq_gather(const float* __restrict__ cb_top,
                          const float* __restrict__ cb_bot,
                          const unsigned long long* __restrict__ keys,
                          const float* __restrict__ x2g,
                          int* __restrict__ counts,
                          float* __restrict__ loss_acc,
                          float* __restrict__ out){
  const int tz = blockIdx.y;
  const float* __restrict__ cbf = tz ? cb_bot : cb_top;
  float* zout = out + (size_t)tz * ((size_t)NQ*DD);
  const int tid = threadIdx.x;
  const int w = tid >> 6, lane = tid & 63;
  const int l32 = lane & 31, half = lane >> 5;
  const int n = blockIdx.x*128 + w*32 + l32;

  unsigned long long key = keys[(size_t)tz*NQ + n];
  const int idx = (int)(key & 1023u);
  const float sc = o2f((unsigned)(key >> 10));

  if (lane < 32) atomicAdd(&counts[tz*KK + idx], 1);
  float ld = (lane < 32) ? (x2g[(size_t)tz*NQ + n] + 2.0f*sc) : 0.0f;
  #pragma unroll
  for (int off = 1; off < 64; off <<= 1) ld += __shfl_xor(ld, off, 64);
  if (lane == 0) atomicAdd(&loss_acc[tz], ld);

  const float* crow = cbf + (size_t)idx*DD + half*128;
  float* zb = zout + (size_t)(n >> 11)*((size_t)DD*TT) + (n & (TT-1))
                   + (size_t)half*128*TT;
  #pragma unroll 4
  for (int dd = 0; dd < 128; dd += 4){
    f32x4 cv = *(const f32x4*)(crow + dd);
    zb[(size_t)(dd+0)*TT] = cv[0];
    zb[(size_t)(dd+1)*TT] = cv[1];
    zb[(size_t)(dd+2)*TT] = cv[2];
    zb[(size_t)(dd+3)*TT] = cv[3];
  }
}

// ---------------------------------------------------------------------------
// Finalize: perplexities + loss scalars. outs = d_out + 2*NQ*DD.
// order: vq_loss, commitment_loss, ppl_top, ppl_bot
// ---------------------------------------------------------------------------
__global__ void vq_final(const int* __restrict__ counts,
                         const float* __restrict__ loss_acc,
                         float* __restrict__ outs){
  __shared__ float red[1024];
  const int tid = threadIdx.x;
  for (int t = 0; t < 2; ++t){
    float p = (float)counts[t*KK + tid] * (1.0f/(float)NQ);
    red[tid] = p * logf(p + 1e-10f);
    __syncthreads();
    for (int s = 512; s > 0; s >>= 1){
      if (tid < s) red[tid] += red[tid + s];
      __syncthreads();
    }
    if (tid == 0) outs[2 + t] = expf(-red[0]);
    __syncthreads();
  }
  if (tid == 0){
    float l = (loss_acc[0] + loss_acc[1]) * (1.0f/8388608.0f);  // mean over B*D*T
    outs[0] = l;   // vq_loss
    outs[1] = l;   // commitment_loss (same forward value)
  }
}

extern "C" void kernel_launch(void* const* d_in, const int* in_sizes, int n_in,
                              void* d_out, int out_size, void* d_ws, size_t ws_size,
                              hipStream_t stream)
{
  (void)in_sizes; (void)n_in; (void)out_size; (void)ws_size;
  const float* h_top  = (const float*)d_in[0];
  const float* h_bot  = (const float*)d_in[1];
  const float* cb_top = (const float*)d_in[2];
  const float* cb_bot = (const float*)d_in[3];
  float* out = (float*)d_out;
  char* ws = (char*)d_ws;

  short* ws_cb    = (short*)ws;                            // 2 MiB
  float* e2h      = (float*)(ws + 0x200000);               // 8 KiB
  int*   counts   = (int*)  (ws + 0x202000);               // 8 KiB
  float* loss_acc = (float*)(ws + 0x204000);               // 64 B
  unsigned long long* keys = (unsigned long long*)(ws + 0x204040);  // 512 KiB
  float* x2g      = (float*)(ws + 0x284040);               // 256 KiB

  vq_prep<<<512, 256, 0, stream>>>(cb_top, cb_bot, ws_cb, e2h, counts, loss_acc, keys);
  vq_main<<<dim3(512, 2), 256, 0, stream>>>(h_top, h_bot, ws_cb, e2h, keys, x2g);
  vq_gather<<<dim3(256, 2), 256, 0, stream>>>(cb_top, cb_bot, keys, x2g,
                                              counts, loss_acc, out);
  vq_final<<<1, 1024, 0, stream>>>(counts, loss_acc, out + (size_t)2*NQ*DD);
}

// Round 5
// 346.124 us; speedup vs baseline: 1.1474x; 1.1474x over previous
//
#include <hip/hip_runtime.h>
#include <stdint.h>

#define TT 2048
#define DD 256
#define KK 1024
#define BB 16
#define NQ (BB*TT)   // 32768 queries per tensor

typedef __attribute__((ext_vector_type(8))) short short8;
typedef __attribute__((ext_vector_type(4))) short s16x4;
typedef __attribute__((ext_vector_type(4))) float f32x4;

__device__ __forceinline__ short bf16_rn(float x){
  unsigned u = __builtin_bit_cast(unsigned, x);
  unsigned r = u + 0x7fffu + ((u >> 16) & 1u);   // round-to-nearest-even
  return (short)(r >> 16);
}
__device__ __forceinline__ float bf16_to_f(short h){
  unsigned u = ((unsigned)(unsigned short)h) << 16;
  return __builtin_bit_cast(float, u);
}

// ---------------------------------------------------------------------------
// Fused prep: one wave per (tensor, code): swizzled bf16 hi/lo codebook,
// 0.5*|e|^2, zero counts/loss.
// Swizzle: code k=(ct*16+c), dim d=(s*32+q*8+j) ->
//   pos = ((ct*8+s)*64 + (q*16+c))*8 + j   (1 KiB per (ct,s) block;
//   lane L=q*16+c reads shorts [pos..pos+7] = contiguous 16 B -> dwordx4)
// ---------------------------------------------------------------------------
__global__ void vq_prep(const float* __restrict__ cb_top,
                        const float* __restrict__ cb_bot,
                        short* __restrict__ ws_cb,
                        float* __restrict__ e2h_all,
                        int* __restrict__ counts,
                        float* __restrict__ loss_acc){
  int gid = blockIdx.x*256 + threadIdx.x;          // 512 blocks -> 2048 waves
  int wv = gid >> 6, lane = gid & 63;
  int t = wv >> 10, k = wv & 1023;
  const float* row = (t ? cb_bot : cb_top) + (size_t)k*DD;
  f32x4 v = *(const f32x4*)(row + lane*4);
  float s2 = v[0]*v[0] + v[1]*v[1] + v[2]*v[2] + v[3]*v[3];
  s16x4 hi4, lo4;
  #pragma unroll
  for (int i = 0; i < 4; ++i){
    short hi = bf16_rn(v[i]);
    hi4[i] = hi;
    lo4[i] = bf16_rn(v[i] - bf16_to_f(hi));
  }
  const int d0 = lane*4;
  const int ct = k >> 4, c = k & 15;
  const int s = d0 >> 5, q = (d0 & 31) >> 3, j = d0 & 7;
  size_t pos = ((size_t)(ct*8 + s)*64 + (q*16 + c))*8 + j;   // j in {0,4}
  short* hib = ws_cb + (size_t)t * (2*KK*DD);
  *(s16x4*)(hib + pos) = hi4;
  *(s16x4*)(hib + (size_t)KK*DD + pos) = lo4;
  #pragma unroll
  for (int off = 1; off < 64; off <<= 1) s2 += __shfl_xor(s2, off, 64);
  if (lane == 0) e2h_all[t*KK + k] = 0.5f * s2;
  if (lane == 1) counts[t*KK + k] = 0;
  if (gid == 2) { loss_acc[0] = 0.f; loss_acc[1] = 0.f; }
}

// ---------------------------------------------------------------------------
// Main: BARRIER-FREE. G=2 (32 q/wave), 3-term bf16-split MFMA argmin.
// A-frags read directly from the L2-resident swizzled codebook (2 MB) as
// coalesced dwordx4 — no LDS, no __syncthreads; waves fully independent so
// HBM prologue/epilogue of some waves overlaps MFMA of others.
// grid (256, 2), block 256 (4 independent waves, 128 q/block).
// ---------------------------------------------------------------------------
__global__ __launch_bounds__(256, 2) void vq_main(
    const float* __restrict__ h_top, const float* __restrict__ h_bot,
    const float* __restrict__ cb_top, const float* __restrict__ cb_bot,
    const short* __restrict__ ws_cb, const float* __restrict__ e2h_all,
    int* __restrict__ counts, float* __restrict__ loss_acc,
    float* __restrict__ out)
{
  const int tz = blockIdx.y;
  const float* __restrict__ h   = tz ? h_bot : h_top;
  const float* __restrict__ cbf = tz ? cb_bot : cb_top;
  const short* cbhi = ws_cb + (size_t)tz * (2*KK*DD);
  const short* cblo = cbhi + KK*DD;
  const float* e2h = e2h_all + tz*KK;
  float* zout = out + (size_t)tz * ((size_t)NQ*DD);

  const int tid = threadIdx.x;
  const int w = tid >> 6, lane = tid & 63;
  const int c = lane & 15, q = lane >> 4;
  const int n0 = blockIdx.x*128 + w*32;             // first query of this wave

  // ---- prologue: 32 q x 256 d -> bf16 hi/lo B-frags + |x|^2.
  //      Loads batched 32-deep before any conversion (memory-level par.) ----
  short8 bhi[2][8], blo[2][8];
  float x2[2];
  #pragma unroll
  for (int g = 0; g < 2; ++g){
    const int n = n0 + g*16 + c;
    const float* bp = h + (size_t)(n >> 11)*((size_t)DD*TT) + (n & (TT-1))
                        + (size_t)q*8*TT;
    float xs = 0.f;
    #pragma unroll
    for (int sh = 0; sh < 2; ++sh){                 // two half-batches of 32
      float v[32];
      #pragma unroll
      for (int i = 0; i < 32; ++i){                 // d = (sh*4+i/8)*32+q*8+(i%8)
        v[i] = bp[(size_t)((sh*4 + (i >> 3))*32 + (i & 7))*TT];
      }
      #pragma unroll
      for (int i = 0; i < 32; ++i){
        float x = v[i];
        xs += x*x;
        short hi = bf16_rn(x);
        bhi[g][sh*4 + (i >> 3)][i & 7] = hi;
        blo[g][sh*4 + (i >> 3)][i & 7] = bf16_rn(x - bf16_to_f(hi));
      }
    }
    x2[g] = xs;
  }

  float bestv[2] = {3.4e38f, 3.4e38f};
  int   besti[2] = {0, 0};

  // ---- main loop: 64 tiles of 16 codes, frags straight from L2 ----
  for (int ct = 0; ct < 64; ++ct){
    const short* abase = cbhi + (size_t)(ct*8)*512 + lane*8;
    f32x4 a0 = {0,0,0,0}, a1 = {0,0,0,0};
    #pragma unroll
    for (int s = 0; s < 8; ++s){
      short8 ahi = *(const short8*)(abase + s*512);
      short8 alo = *(const short8*)(abase + KK*DD + s*512);
      a0 = __builtin_amdgcn_mfma_f32_16x16x32_bf16(ahi, bhi[0][s], a0, 0,0,0);
      a1 = __builtin_amdgcn_mfma_f32_16x16x32_bf16(ahi, bhi[1][s], a1, 0,0,0);
      a0 = __builtin_amdgcn_mfma_f32_16x16x32_bf16(ahi, blo[0][s], a0, 0,0,0);
      a1 = __builtin_amdgcn_mfma_f32_16x16x32_bf16(ahi, blo[1][s], a1, 0,0,0);
      a0 = __builtin_amdgcn_mfma_f32_16x16x32_bf16(alo, bhi[0][s], a0, 0,0,0);
      a1 = __builtin_amdgcn_mfma_f32_16x16x32_bf16(alo, bhi[1][s], a1, 0,0,0);
    }
    const int code0 = ct*16 + q*4;                  // C: row=code, col=query
    const f32x4 e2v = *(const f32x4*)(e2h + code0);
    #pragma unroll
    for (int r = 0; r < 4; ++r){
      float s0 = e2v[r] - a0[r];                    // = (dist - |x|^2)/2
      if (s0 < bestv[0]){ bestv[0] = s0; besti[0] = code0 + r; }
      float s1 = e2v[r] - a1[r];
      if (s1 < bestv[1]){ bestv[1] = s1; besti[1] = code0 + r; }
    }
  }

  // ---- reduce across the 4 quads (codes are quad-partitioned) ----
  #pragma unroll
  for (int off = 16; off <= 32; off <<= 1){
    #pragma unroll
    for (int g = 0; g < 2; ++g){
      float ov = __shfl_xor(bestv[g], off, 64);
      int   oi = __shfl_xor(besti[g], off, 64);
      if (ov < bestv[g] || (ov == bestv[g] && oi < besti[g])){ bestv[g] = ov; besti[g] = oi; }
      x2[g] += __shfl_xor(x2[g], off, 64);
    }
  }

  // lane L < 32 owns query n0 + L  (g = L>>4, c = L&15)
  const int gsel = (lane >> 4) & 1;
  const int j32 = lane & 31;
  const int n = n0 + j32;
  float bv = gsel ? bestv[1] : bestv[0];
  int   bi = gsel ? besti[1] : besti[0];
  float xx = gsel ? x2[1]    : x2[0];

  if (lane < 32) atomicAdd(&counts[tz*KK + bi], 1);

  float ld = (lane < 32) ? (xx + 2.0f*bv) : 0.0f;   // dist = |x|^2 + 2*score
  #pragma unroll
  for (int off = 1; off < 64; off <<= 1) ld += __shfl_xor(ld, off, 64);
  if (lane == 0) atomicAdd(&loss_acc[tz], ld);

  // ---- z = codebook[idx] in [B,D,T] layout; 64 lanes split d in halves,
  //      32 lanes x 4 B = 128 B contiguous per store ----
  const int half = lane >> 5;
  const float* crow = cbf + (size_t)bi * DD + half*128;
  float* zb = zout + (size_t)(n >> 11)*((size_t)DD*TT) + (n & (TT-1))
                   + (size_t)half*128*TT;
  #pragma unroll 4
  for (int dd = 0; dd < 128; dd += 4){
    f32x4 cv = *(const f32x4*)(crow + dd);
    zb[(size_t)(dd+0)*TT] = cv[0];
    zb[(size_t)(dd+1)*TT] = cv[1];
    zb[(size_t)(dd+2)*TT] = cv[2];
    zb[(size_t)(dd+3)*TT] = cv[3];
  }
}

// ---------------------------------------------------------------------------
// Finalize: perplexities + loss scalars. outs = d_out + 2*NQ*DD.
// order: vq_loss, commitment_loss, ppl_top, ppl_bot
// ---------------------------------------------------------------------------
__global__ void vq_final(const int* __restrict__ counts,
                         const float* __restrict__ loss_acc,
                         float* __restrict__ outs){
  __shared__ float red[1024];
  const int tid = threadIdx.x;
  for (int t = 0; t < 2; ++t){
    float p = (float)counts[t*KK + tid] * (1.0f/(float)NQ);
    red[tid] = p * logf(p + 1e-10f);
    __syncthreads();
    for (int s = 512; s > 0; s >>= 1){
      if (tid < s) red[tid] += red[tid + s];
      __syncthreads();
    }
    if (tid == 0) outs[2 + t] = expf(-red[0]);
    __syncthreads();
  }
  if (tid == 0){
    float l = (loss_acc[0] + loss_acc[1]) * (1.0f/8388608.0f);  // mean over B*D*T
    outs[0] = l;   // vq_loss
    outs[1] = l;   // commitment_loss (same forward value)
  }
}

extern "C" void kernel_launch(void* const* d_in, const int* in_sizes, int n_in,
                              void* d_out, int out_size, void* d_ws, size_t ws_size,
                              hipStream_t stream)
{
  (void)in_sizes; (void)n_in; (void)out_size; (void)ws_size;
  const float* h_top  = (const float*)d_in[0];
  const float* h_bot  = (const float*)d_in[1];
  const float* cb_top = (const float*)d_in[2];
  const float* cb_bot = (const float*)d_in[3];
  float* out = (float*)d_out;
  char* ws = (char*)d_ws;

  short* ws_cb    = (short*)ws;                          // 2 MiB
  float* e2h      = (float*)(ws + 0x200000);             // 8 KiB
  int*   counts   = (int*)  (ws + 0x202000);             // 8 KiB
  float* loss_acc = (float*)(ws + 0x204000);             // 64 B

  vq_prep<<<512, 256, 0, stream>>>(cb_top, cb_bot, ws_cb, e2h, counts, loss_acc);
  vq_main<<<dim3(256, 2), 256, 0, stream>>>(h_top, h_bot, cb_top, cb_bot,
                                            ws_cb, e2h, counts, loss_acc, out);
  vq_final<<<1, 1024, 0, stream>>>(counts, loss_acc, out + (size_t)2*NQ*DD);
}

// Round 6
// 345.905 us; speedup vs baseline: 1.1481x; 1.0006x over previous
//
#include <hip/hip_runtime.h>
#include <stdint.h>

#define TT 2048
#define DD 256
#define KK 1024
#define BB 16
#define NQ (BB*TT)   // 32768 queries per tensor

typedef __attribute__((ext_vector_type(8))) short short8;
typedef __attribute__((ext_vector_type(4))) short s16x4;
typedef __attribute__((ext_vector_type(4))) float f32x4;

__device__ __forceinline__ short bf16_rn(float x){
  unsigned u = __builtin_bit_cast(unsigned, x);
  unsigned r = u + 0x7fffu + ((u >> 16) & 1u);   // round-to-nearest-even
  return (short)(r >> 16);
}
__device__ __forceinline__ float bf16_to_f(short h){
  unsigned u = ((unsigned)(unsigned short)h) << 16;
  return __builtin_bit_cast(float, u);
}

// ---------------------------------------------------------------------------
// Prep: one wave per (tensor, code): swizzled bf16 hi/lo codebook, 0.5*|e|^2,
// zero counts/loss.  Swizzle: code k=(ct*16+c), dim d=(s*32+q*8+j) ->
//   pos = ((ct*8+s)*64 + (q*16+c))*8 + j
// so MFMA lane L=q*16+c reads a contiguous 16 B (dwordx4) per (ct,s).
// ---------------------------------------------------------------------------
__global__ void vq_prep(const float* __restrict__ cb_top,
                        const float* __restrict__ cb_bot,
                        short* __restrict__ ws_cb,
                        float* __restrict__ e2h_all,
                        int* __restrict__ counts,
                        float* __restrict__ loss_acc){
  int gid = blockIdx.x*256 + threadIdx.x;          // 512 blocks -> 2048 waves
  int wv = gid >> 6, lane = gid & 63;
  int t = wv >> 10, k = wv & 1023;
  const float* row = (t ? cb_bot : cb_top) + (size_t)k*DD;
  f32x4 v = *(const f32x4*)(row + lane*4);
  float s2 = v[0]*v[0] + v[1]*v[1] + v[2]*v[2] + v[3]*v[3];
  s16x4 hi4, lo4;
  #pragma unroll
  for (int i = 0; i < 4; ++i){
    short hi = bf16_rn(v[i]);
    hi4[i] = hi;
    lo4[i] = bf16_rn(v[i] - bf16_to_f(hi));
  }
  const int d0 = lane*4;
  const int ct = k >> 4, c = k & 15;
  const int s = d0 >> 5, q = (d0 & 31) >> 3, j = d0 & 7;
  size_t pos = ((size_t)(ct*8 + s)*64 + (q*16 + c))*8 + j;   // j in {0,4}
  short* hib = ws_cb + (size_t)t * (2*KK*DD);
  *(s16x4*)(hib + pos) = hi4;
  *(s16x4*)(hib + (size_t)KK*DD + pos) = lo4;
  #pragma unroll
  for (int off = 1; off < 64; off <<= 1) s2 += __shfl_xor(s2, off, 64);
  if (lane == 0) e2h_all[t*KK + k] = 0.5f * s2;
  if (lane == 1) counts[t*KK + k] = 0;
  if (gid == 2) { loss_acc[0] = 0.f; loss_acc[1] = 0.f; }
}

// ---------------------------------------------------------------------------
// Main: block = 32 queries (B-frags in LDS, shared/broadcast); each of the
// 4 waves scans a 256-code quarter of the codebook, A-frags streamed from
// the L2-resident swizzled codebook with 1-step register prefetch, 2 code-
// tiles per b-frag ds_read (12 MFMA / 4 ds_read_b128).  Barrier-free scan;
// in-block merge via LDS.  grid (1024, 2), block 256.
// ---------------------------------------------------------------------------
__global__ __launch_bounds__(256, 3) void vq_main(
    const float* __restrict__ h_top, const float* __restrict__ h_bot,
    const float* __restrict__ cb_top, const float* __restrict__ cb_bot,
    const short* __restrict__ ws_cb, const float* __restrict__ e2h_all,
    int* __restrict__ counts, float* __restrict__ loss_acc,
    float* __restrict__ out)
{
  const int tz = blockIdx.y;
  const float* __restrict__ h   = tz ? h_bot : h_top;
  const float* __restrict__ cbf = tz ? cb_bot : cb_top;
  const short* cwz = ws_cb + (size_t)tz * (2*KK*DD);   // hi base; lo at +KK*DD
  const float* e2h = e2h_all + tz*KK;
  float* zout = out + (size_t)tz * ((size_t)NQ*DD);

  const int t = threadIdx.x;
  const int w = t >> 6, lane = t & 63;
  const int n0 = blockIdx.x*32;                     // block queries n0..n0+31
  const int b = n0 >> 11, tq0 = n0 & (TT-1);        // same b for all 32

  __shared__ short bfh[2][8][64][8];                // 16 KiB  B-frags hi
  __shared__ short bfl[2][8][64][8];                // 16 KiB  B-frags lo
  __shared__ float x2p[8][32];                      // per-(s,query) |x|^2 part
  __shared__ float mvv[4][32];                      // per-wave best value
  __shared__ int   mii[4][32];                      // per-wave best index
  __shared__ int   idxs[32];

  // ---- prologue: build B-frags in LDS.  thread t: query q32=t&31, s=t>>5 ---
  {
    const int q32 = t & 31, s = t >> 5;
    const int g = q32 >> 4, c = q32 & 15;
    const float* hp = h + ((size_t)b*DD + s*32)*TT + (tq0 + q32);
    float v[32];
    #pragma unroll
    for (int dd = 0; dd < 32; ++dd) v[dd] = hp[(size_t)dd*TT];
    float xs = 0.f;
    #pragma unroll
    for (int qp = 0; qp < 4; ++qp){
      short8 hi8, lo8;
      #pragma unroll
      for (int j = 0; j < 8; ++j){
        float x = v[qp*8 + j];
        xs += x*x;
        short hi = bf16_rn(x);
        hi8[j] = hi;
        lo8[j] = bf16_rn(x - bf16_to_f(hi));
      }
      *(short8*)&bfh[g][s][qp*16 + c][0] = hi8;
      *(short8*)&bfl[g][s][qp*16 + c][0] = lo8;
    }
    x2p[s][q32] = xs;
  }
  __syncthreads();

  // ---- scan: wave w covers code-tiles [w*16, w*16+16), 8 pairs ----
  float bestv[2] = {3.4e38f, 3.4e38f};
  int   besti[2] = {0, 0};
  const int wb = w*16;
  const int q4 = lane >> 4;

  #define LDA(CT, s, hl) \
    (*(const short8*)(cwz + (hl)*(KK*DD) + ((size_t)((CT)*8 + (s))*64 + lane)*8))

  short8 a0h = LDA(wb,   0, 0), a0l = LDA(wb,   0, 1);
  short8 a1h = LDA(wb+1, 0, 0), a1l = LDA(wb+1, 0, 1);

  for (int u = 0; u < 8; ++u){
    const int CT0 = wb + 2*u;
    f32x4 acc00 = {0,0,0,0}, acc01 = {0,0,0,0};    // tile0 x {g0,g1}
    f32x4 acc10 = {0,0,0,0}, acc11 = {0,0,0,0};    // tile1 x {g0,g1}
    #pragma unroll
    for (int s = 0; s < 8; ++s){
      short8 b0h = *(const short8*)&bfh[0][s][lane][0];
      short8 b0l = *(const short8*)&bfl[0][s][lane][0];
      short8 b1h = *(const short8*)&bfh[1][s][lane][0];
      short8 b1l = *(const short8*)&bfl[1][s][lane][0];
      // prefetch next (s+1, or next pair's s=0; last iter reloads wb, unused)
      const int ns  = (s + 1) & 7;
      const int nCT = (s == 7) ? ((u == 7) ? wb : CT0 + 2) : CT0;
      short8 na0h = LDA(nCT,   ns, 0), na0l = LDA(nCT,   ns, 1);
      short8 na1h = LDA(nCT+1, ns, 0), na1l = LDA(nCT+1, ns, 1);
      acc00 = __builtin_amdgcn_mfma_f32_16x16x32_bf16(a0h, b0h, acc00, 0,0,0);
      acc01 = __builtin_amdgcn_mfma_f32_16x16x32_bf16(a0h, b1h, acc01, 0,0,0);
      acc10 = __builtin_amdgcn_mfma_f32_16x16x32_bf16(a1h, b0h, acc10, 0,0,0);
      acc11 = __builtin_amdgcn_mfma_f32_16x16x32_bf16(a1h, b1h, acc11, 0,0,0);
      acc00 = __builtin_amdgcn_mfma_f32_16x16x32_bf16(a0h, b0l, acc00, 0,0,0);
      acc01 = __builtin_amdgcn_mfma_f32_16x16x32_bf16(a0h, b1l, acc01, 0,0,0);
      acc10 = __builtin_amdgcn_mfma_f32_16x16x32_bf16(a1h, b0l, acc10, 0,0,0);
      acc11 = __builtin_amdgcn_mfma_f32_16x16x32_bf16(a1h, b1l, acc11, 0,0,0);
      acc00 = __builtin_amdgcn_mfma_f32_16x16x32_bf16(a0l, b0h, acc00, 0,0,0);
      acc01 = __builtin_amdgcn_mfma_f32_16x16x32_bf16(a0l, b1h, acc01, 0,0,0);
      acc10 = __builtin_amdgcn_mfma_f32_16x16x32_bf16(a1l, b0h, acc10, 0,0,0);
      acc11 = __builtin_amdgcn_mfma_f32_16x16x32_bf16(a1l, b1h, acc11, 0,0,0);
      a0h = na0h; a0l = na0l; a1h = na1h; a1l = na1l;
    }
    // epilogue: C row=code-in-tile (q4*4+r), col=query
    const int code0 = CT0*16 + q4*4;
    const int code1 = code0 + 16;
    const f32x4 e20 = *(const f32x4*)(e2h + code0);
    const f32x4 e21 = *(const f32x4*)(e2h + code1);
    #pragma unroll
    for (int r = 0; r < 4; ++r){
      float s00 = e20[r] - acc00[r];                // = (dist - |x|^2)/2
      if (s00 < bestv[0]){ bestv[0] = s00; besti[0] = code0 + r; }
      float s01 = e20[r] - acc01[r];
      if (s01 < bestv[1]){ bestv[1] = s01; besti[1] = code0 + r; }
      float s10 = e21[r] - acc10[r];
      if (s10 < bestv[0]){ bestv[0] = s10; besti[0] = code1 + r; }
      float s11 = e21[r] - acc11[r];
      if (s11 < bestv[1]){ bestv[1] = s11; besti[1] = code1 + r; }
    }
  }
  #undef LDA

  // ---- quad-reduce within wave (codes are quad-partitioned) ----
  #pragma unroll
  for (int off = 16; off <= 32; off <<= 1){
    #pragma unroll
    for (int g = 0; g < 2; ++g){
      float ov = __shfl_xor(bestv[g], off, 64);
      int   oi = __shfl_xor(besti[g], off, 64);
      if (ov < bestv[g] || (ov == bestv[g] && oi < besti[g])){ bestv[g] = ov; besti[g] = oi; }
    }
  }
  if (lane < 32){                                   // lane L: query L
    const int gsel = (lane >> 4) & 1;
    mvv[w][lane] = gsel ? bestv[1] : bestv[0];
    mii[w][lane] = gsel ? besti[1] : besti[0];
  }
  __syncthreads();

  // ---- merge across the 4 waves + counts/loss (wave 0) ----
  float ld = 0.f;
  if (t < 32){
    float bv = mvv[0][t]; int bi = mii[0][t];
    #pragma unroll
    for (int wp = 1; wp < 4; ++wp){
      float ov = mvv[wp][t]; int oi = mii[wp][t];
      if (ov < bv || (ov == bv && oi < bi)){ bv = ov; bi = oi; }
    }
    idxs[t] = bi;
    float xx = 0.f;
    #pragma unroll
    for (int s = 0; s < 8; ++s) xx += x2p[s][t];
    atomicAdd(&counts[tz*KK + bi], 1);
    ld = xx + 2.0f*bv;                              // dist = |x|^2 + 2*score
  }
  if (t < 64){
    #pragma unroll
    for (int off = 1; off < 64; off <<= 1) ld += __shfl_xor(ld, off, 64);
    if (t == 0) atomicAdd(&loss_acc[tz], ld);
  }
  __syncthreads();

  // ---- z = codebook[idx], [B,D,T] layout; thread t: query t&31, d-group t>>5
  {
    const int q = t & 31, dg = t >> 5;
    const int idx = idxs[q];
    const float* crow = cbf + (size_t)idx*DD + dg*32;
    float* zb = zout + ((size_t)b*DD + dg*32)*TT + (tq0 + q);
    #pragma unroll
    for (int i = 0; i < 32; i += 4){
      f32x4 cv = *(const f32x4*)(crow + i);
      zb[(size_t)(i+0)*TT] = cv[0];
      zb[(size_t)(i+1)*TT] = cv[1];
      zb[(size_t)(i+2)*TT] = cv[2];
      zb[(size_t)(i+3)*TT] = cv[3];
    }
  }
}

// ---------------------------------------------------------------------------
// Finalize: perplexities + loss scalars. outs = d_out + 2*NQ*DD.
// order: vq_loss, commitment_loss, ppl_top, ppl_bot
// ---------------------------------------------------------------------------
__global__ void vq_final(const int* __restrict__ counts,
                         const float* __restrict__ loss_acc,
                         float* __restrict__ outs){
  __shared__ float red[1024];
  const int tid = threadIdx.x;
  for (int t = 0; t < 2; ++t){
    float p = (float)counts[t*KK + tid] * (1.0f/(float)NQ);
    red[tid] = p * logf(p + 1e-10f);
    __syncthreads();
    for (int s = 512; s > 0; s >>= 1){
      if (tid < s) red[tid] += red[tid + s];
      __syncthreads();
    }
    if (tid == 0) outs[2 + t] = expf(-red[0]);
    __syncthreads();
  }
  if (tid == 0){
    float l = (loss_acc[0] + loss_acc[1]) * (1.0f/8388608.0f);  // mean over B*D*T
    outs[0] = l;   // vq_loss
    outs[1] = l;   // commitment_loss (same forward value)
  }
}

extern "C" void kernel_launch(void* const* d_in, const int* in_sizes, int n_in,
                              void* d_out, int out_size, void* d_ws, size_t ws_size,
                              hipStream_t stream)
{
  (void)in_sizes; (void)n_in; (void)out_size; (void)ws_size;
  const float* h_top  = (const float*)d_in[0];
  const float* h_bot  = (const float*)d_in[1];
  const float* cb_top = (const float*)d_in[2];
  const float* cb_bot = (const float*)d_in[3];
  float* out = (float*)d_out;
  char* ws = (char*)d_ws;

  short* ws_cb    = (short*)ws;                          // 2 MiB
  float* e2h      = (float*)(ws + 0x200000);             // 8 KiB
  int*   counts   = (int*)  (ws + 0x202000);             // 8 KiB
  float* loss_acc = (float*)(ws + 0x204000);             // 64 B

  vq_prep<<<512, 256, 0, stream>>>(cb_top, cb_bot, ws_cb, e2h, counts, loss_acc);
  vq_main<<<dim3(1024, 2), 256, 0, stream>>>(h_top, h_bot, cb_top, cb_bot,
                                             ws_cb, e2h, counts, loss_acc, out);
  vq_final<<<1, 1024, 0, stream>>>(counts, loss_acc, out + (size_t)2*NQ*DD);
}